// Round 6
// baseline (266.235 us; speedup 1.0000x reference)
//
#include <hip/hip_runtime.h>
#include <cstdint>

#define DEV __device__ __forceinline__

typedef float f32x4 __attribute__((ext_vector_type(4)));
typedef short s16x8 __attribute__((ext_vector_type(8)));

DEV unsigned short f2bf(float f){
    unsigned u = __builtin_bit_cast(unsigned, f);
    u = u + 0x7fffu + ((u >> 16) & 1u);   // RNE
    return (unsigned short)(u >> 16);
}
DEV float bf2f(unsigned short h){
    unsigned u = ((unsigned)h) << 16;
    return __builtin_bit_cast(float, u);
}

typedef const void __attribute__((address_space(1)))* gcp;
typedef void __attribute__((address_space(3)))* lp;
DEV void gload_lds16(const void* g, void* l){
    // async global->LDS, 16B per lane; LDS dest = wave-uniform base + lane*16
    __builtin_amdgcn_global_load_lds((gcp)g, (lp)l, 16, 0, 0);
}

#define SCALE_QK 0.04419417382415922f   // 1/sqrt(512)

// ---------------------------------------------------------------------------
// Dragon pattern: fully input-independent -> computed at COMPILE TIME.
// patterns[11] has length 4095 = 2*2048-1; np.interp to 2048 picks a[2i].
// ---------------------------------------------------------------------------
struct Pat2 { float v[2048]; };
constexpr Pat2 make_pat2(){
    float a[4095] = {}; float b[4095] = {};
    a[0] = 0.5f; int len = 1;
    for (int it = 1; it < 12; ++it){
        int n = len, nl = 2*n + 1;
        // expand: [prev, 0.5, 1 - reverse(prev)]
        for (int i = 0; i < nl; ++i)
            b[i] = (i < n) ? a[i] : ((i == n) ? 0.5f : 1.0f - a[2*n - i]);
        // conv1d [1/3,1/3,1/3], zero pad 'same'; fused min/max
        const float third = 1.0f/3.0f;
        float mn = 3.4e38f, mx = -3.4e38f;
        for (int i = 0; i < nl; ++i){
            float s = b[i]*third;
            if (i > 0)      s += b[i-1]*third;
            if (i < nl - 1) s += b[i+1]*third;
            a[i] = s;
            mn = (s < mn) ? s : mn;
            mx = (s > mx) ? s : mx;
        }
        float d = mx - mn + 1e-8f;
        for (int i = 0; i < nl; ++i) a[i] = (a[i] - mn) / d;
        len = nl;
    }
    Pat2 p{};
    for (int i = 0; i < 2048; ++i) p.v[i] = a[2*i];
    return p;
}
__device__ const Pat2 g_pat2 = make_pat2();

// ---------------------------------------------------------------------------
// Conv (grid 3072, pure streaming — no stragglers):
//   blocks 0..1023   : Q -> bf16, K -> bf16 (raw; dragon weight applied in
//                      gemm_qk epilogue via the identity Q.(Kw)^T = (Q.K^T)w)
//   blocks 1024..3071: V -> Vt (bf16 [b][d][s]) + vmean atomics
// ---------------------------------------------------------------------------
__global__ __launch_bounds__(256) void k_conv(
    const float* __restrict__ Q, const float* __restrict__ K,
    const float* __restrict__ V,
    unsigned short* __restrict__ Qb, unsigned short* __restrict__ Kb,
    unsigned short* __restrict__ Vt, float* __restrict__ vmean)
{
    __shared__ float sh[4480];
    int tid = threadIdx.x;
    int bx  = blockIdx.x;

    if (bx < 1024){
        const long long total4 = (long long)8*2048*512/4;   // 2097152
        long long stride = 1024LL*256;
        for (long long i = (long long)bx*256 + tid; i < total4; i += stride){
            long long base = i*4;
            const float4 q = *(const float4*)(Q + base);
            const float4 k = *(const float4*)(K + base);
            ushort4 qo, ko;
            qo.x = f2bf(q.x); qo.y = f2bf(q.y); qo.z = f2bf(q.z); qo.w = f2bf(q.w);
            ko.x = f2bf(k.x); ko.y = f2bf(k.y); ko.z = f2bf(k.z); ko.w = f2bf(k.w);
            *(ushort4*)(Qb + base) = qo;
            *(ushort4*)(Kb + base) = ko;
        }
        return;
    }

    // ---- V transpose + vmean atomics ----
    int t = bx - 1024;                    // 0..2047 = 32 stile x 8 dtile x 8 b
    int stile = t & 31, dtile = (t >> 5) & 7, b = t >> 8;
    int s0 = stile*64, d0 = dtile*64;
    float (*tile)[66] = (float(*)[66])sh;  // 64x66 = 4224 floats
    float* red = sh + 4224;                // 256 floats
    int tx = tid & 63, ty = tid >> 6;
    const float* src = V + ((long long)b*2048 + s0)*512 + d0;
    #pragma unroll
    for (int r = 0; r < 16; ++r){
        int row = r*4 + ty;
        tile[row][tx] = src[(long long)row*512 + tx];
    }
    __syncthreads();
    unsigned short* dst = Vt + ((long long)b*512 + d0)*2048 + s0;
    #pragma unroll
    for (int r = 0; r < 16; ++r){
        int drow = r*4 + ty;
        dst[(long long)drow*2048 + tx] = f2bf(tile[tx][drow]);
    }
    int dcol = tid & 63, sp = tid >> 6;
    float s = 0.f;
    #pragma unroll
    for (int ii = 0; ii < 16; ++ii) s += tile[sp*16 + ii][dcol];
    red[sp*64 + dcol] = s;
    __syncthreads();
    if (sp == 0){
        float tot = red[dcol] + red[64+dcol] + red[128+dcol] + red[192+dcol];
        atomicAdd(&vmean[b*512 + d0 + dcol], tot * (1.0f/2048.0f));
    }
}

// ---------------------------------------------------------------------------
// GEMM 1: Sp[b,q,k] = bf16( exp( (Qb . Kb^T) * softplus(pat[k]*sc+bi)/sqrt(D) ))
// 128x128 tile (proven sweet spot: 88 VGPR), BK=64, 4 waves (2x2), 4x4 MFMA.
// XOR-swizzled LDS -> 0 bank conflicts. Epilogue repacks C through LDS
// (pad 140 -> conflict-free) for dwordx4 coalesced Sp stores.
// ---------------------------------------------------------------------------
#define EPAD 140

__global__ __launch_bounds__(256) void k_gemm_qk(
    const unsigned short* __restrict__ Qb, const unsigned short* __restrict__ Kb,
    const float* __restrict__ scale, const float* __restrict__ bias,
    unsigned short* __restrict__ Sp)
{
    __shared__ unsigned short smem[128*EPAD];   // staging (2x8192) + epilogue tile
    unsigned short* At = smem;
    unsigned short* Bt = smem + 8192;
    int tid = threadIdx.x;
    int lane = tid & 63, wave = tid >> 6;
    int wm = wave >> 1, wn = wave & 1;
    int ln = lane & 15, q4 = lane >> 4;
    int sx = ln & 7;
    int q0 = blockIdx.y*128, k0 = blockIdx.x*128, b = blockIdx.z;
    const unsigned short* Abase = Qb + ((long long)b*2048 + q0)*512;
    const unsigned short* Bbase = Kb + ((long long)b*2048 + k0)*512;

    f32x4 acc[4][4];
    #pragma unroll
    for (int i = 0; i < 4; ++i)
        #pragma unroll
        for (int j = 0; j < 4; ++j) acc[i][j] = (f32x4)0.0f;

    int cc = lane & 7, rg = lane >> 3;
    for (int kt = 0; kt < 8; ++kt){
        #pragma unroll
        for (int c = 0; c < 4; ++c){
            int chunk = wave*4 + c;                 // 16 x 1KB chunks per tile
            int row = chunk*8 + rg;
            int gc  = cc ^ (row & 7);               // swizzled source chunk
            gload_lds16(Abase + (long long)row*512 + kt*64 + gc*8, &At[chunk*512]);
            gload_lds16(Bbase + (long long)row*512 + kt*64 + gc*8, &Bt[chunk*512]);
        }
        __syncthreads();
        #pragma unroll
        for (int ks = 0; ks < 2; ++ks){
            int cs = ((ks*4 + q4) ^ sx) * 8;        // swizzled fragment chunk
            s16x8 af[4], bfr[4];
            #pragma unroll
            for (int i = 0; i < 4; ++i)
                af[i] = *(const s16x8*)&At[(wm*64 + i*16 + ln)*64 + cs];
            #pragma unroll
            for (int j = 0; j < 4; ++j)
                bfr[j] = *(const s16x8*)&Bt[(wn*64 + j*16 + ln)*64 + cs];
            #pragma unroll
            for (int i = 0; i < 4; ++i)
                #pragma unroll
                for (int j = 0; j < 4; ++j)
                    acc[i][j] = __builtin_amdgcn_mfma_f32_16x16x32_bf16(af[i], bfr[j], acc[i][j], 0, 0, 0);
        }
        __syncthreads();
    }

    // ---- epilogue: dragon weight (compile-time pattern + runtime affine),
    //      exp, LDS repack, coalesced dwordx4 stores ----
    float sc = scale[11], bi = bias[11];
    float wq[4];
    #pragma unroll
    for (int j = 0; j < 4; ++j){
        float x = g_pat2.v[k0 + wn*64 + j*16 + ln]*sc + bi;
        wq[j] = (fmaxf(x, 0.f) + log1pf(__expf(-fabsf(x)))) * SCALE_QK;  // softplus
    }
    #pragma unroll
    for (int i = 0; i < 4; ++i)
        #pragma unroll
        for (int j = 0; j < 4; ++j)
            #pragma unroll
            for (int r = 0; r < 4; ++r){
                int ql = wm*64 + i*16 + q4*4 + r;   // C/D: row=(lane>>4)*4+reg
                int kl = wn*64 + j*16 + ln;         //      col=lane&15
                smem[ql*EPAD + kl] = f2bf(__expf(acc[i][j][r] * wq[j]));
            }
    __syncthreads();
    int row = tid >> 1, half = tid & 1;
    unsigned short* dstp = Sp + (long long)b*2048*2048
                              + (long long)(q0 + row)*2048 + k0 + half*64;
    const unsigned short* srcp = &smem[row*EPAD + half*64];
    #pragma unroll
    for (int u = 0; u < 8; ++u)
        *(s16x8*)(dstp + u*8) = *(const s16x8*)(srcp + u*8);
}

// ---------------------------------------------------------------------------
// GEMM 2: out[b,q,d] = blend * (Sp . V) / l[q] + (1-blend) * Vmean[d]
// l[q] = sum_k Sp[q,k] from the A-fragments (wn==0 waves only).
// blend's 12->64->1 MLP computed redundantly by wave 0 (hidden behind staging).
// Grid flattened, XCD-aware decode: 4 d-tiles of one (q,b) pair land on the
// same XCD -> Sp rows fetched ~once per pair.
// ---------------------------------------------------------------------------
__global__ __launch_bounds__(256) void k_gemm_pv(
    const unsigned short* __restrict__ Sp, const unsigned short* __restrict__ Vt,
    const float* __restrict__ vmean,
    const float* __restrict__ w1, const float* __restrict__ b1,
    const float* __restrict__ w2, const float* __restrict__ b2,
    float* __restrict__ out)
{
    __shared__ unsigned short At[128*64];
    __shared__ unsigned short Bt[128*64];
    __shared__ float l_sh[128];
    __shared__ float sh_blend;
    int tid = threadIdx.x;
    int lane = tid & 63, wave = tid >> 6;
    int wm = wave >> 1, wn = wave & 1;
    int ln = lane & 15, q4 = lane >> 4;
    int sx = ln & 7;

    // blend (tiny MLP) on wave 0, before staging loop
    if (wave == 0){
        float h = fmaxf(w1[11*64 + lane] + b1[lane], 0.f);
        float c = h * w2[lane];
        #pragma unroll
        for (int off = 32; off > 0; off >>= 1) c += __shfl_xor(c, off, 64);
        if (lane == 0) sh_blend = 1.f/(1.f + __expf(-(c + b2[0])));
    }

    // XCD-aware decode
    int g    = blockIdx.x;             // 0..511
    int xcd  = g & 7, slot = g >> 3;   // slot 0..63
    int pair = xcd*16 + (slot >> 2);   // 0..127
    int dt   = slot & 3;
    int qt   = pair & 15, b = pair >> 4;
    int q0 = qt*128, d0 = dt*128;

    const unsigned short* Abase = Sp + (long long)b*2048*2048 + (long long)q0*2048;
    const unsigned short* Bbase = Vt + ((long long)b*512 + d0)*2048;

    f32x4 acc[4][4];
    #pragma unroll
    for (int i = 0; i < 4; ++i)
        #pragma unroll
        for (int j = 0; j < 4; ++j) acc[i][j] = (f32x4)0.0f;
    float lsum[4] = {0.f, 0.f, 0.f, 0.f};

    int cc = lane & 7, rg = lane >> 3;
    for (int kt = 0; kt < 32; ++kt){
        #pragma unroll
        for (int c = 0; c < 4; ++c){
            int chunk = wave*4 + c;
            int row = chunk*8 + rg;
            int gc  = cc ^ (row & 7);
            gload_lds16(Abase + (long long)row*2048 + kt*64 + gc*8, &At[chunk*512]);
            gload_lds16(Bbase + (long long)row*2048 + kt*64 + gc*8, &Bt[chunk*512]);
        }
        __syncthreads();
        #pragma unroll
        for (int ks = 0; ks < 2; ++ks){
            int cs = ((ks*4 + q4) ^ sx) * 8;
            s16x8 af[4], bfr[4];
            #pragma unroll
            for (int i = 0; i < 4; ++i)
                af[i] = *(const s16x8*)&At[(wm*64 + i*16 + ln)*64 + cs];
            #pragma unroll
            for (int j = 0; j < 4; ++j)
                bfr[j] = *(const s16x8*)&Bt[(wn*64 + j*16 + ln)*64 + cs];
            if (wn == 0){
                #pragma unroll
                for (int i = 0; i < 4; ++i){
                    float s = 0.f;
                    #pragma unroll
                    for (int jj = 0; jj < 8; ++jj) s += bf2f((unsigned short)af[i][jj]);
                    lsum[i] += s;
                }
            }
            #pragma unroll
            for (int i = 0; i < 4; ++i)
                #pragma unroll
                for (int j = 0; j < 4; ++j)
                    acc[i][j] = __builtin_amdgcn_mfma_f32_16x16x32_bf16(af[i], bfr[j], acc[i][j], 0, 0, 0);
        }
        __syncthreads();
    }
    if (wn == 0){
        #pragma unroll
        for (int i = 0; i < 4; ++i){
            float v = lsum[i];
            v += __shfl_xor(v, 16, 64);
            v += __shfl_xor(v, 32, 64);
            if (lane < 16) l_sh[wm*64 + i*16 + lane] = v;
        }
    }
    __syncthreads();

    float blend = sh_blend;
    float ib = 1.0f - blend;
    float* obase = out + ((long long)b*2048 + q0)*512 + d0;
    float vm[4];
    #pragma unroll
    for (int j = 0; j < 4; ++j) vm[j] = vmean[b*512 + d0 + wn*64 + j*16 + ln];
    #pragma unroll
    for (int i = 0; i < 4; ++i){
        #pragma unroll
        for (int r = 0; r < 4; ++r){
            int ql = wm*64 + i*16 + q4*4 + r;
            float linv = 1.0f / l_sh[ql];
            #pragma unroll
            for (int j = 0; j < 4; ++j){
                int dl = wn*64 + j*16 + ln;
                obase[(long long)ql*512 + dl] = blend*acc[i][j][r]*linv + ib*vm[j];
            }
        }
    }
}

// ---------------------------------------------------------------------------
extern "C" void kernel_launch(void* const* d_in, const int* in_sizes, int n_in,
                              void* d_out, int out_size, void* d_ws, size_t ws_size,
                              hipStream_t stream)
{
    (void)in_sizes; (void)n_in; (void)out_size; (void)ws_size;
    const float* Q  = (const float*)d_in[0];
    const float* K  = (const float*)d_in[1];
    const float* V  = (const float*)d_in[2];
    const float* ps = (const float*)d_in[3];
    const float* pb = (const float*)d_in[4];
    const float* w1 = (const float*)d_in[5];
    const float* b1 = (const float*)d_in[6];
    const float* w2 = (const float*)d_in[7];
    const float* b2 = (const float*)d_in[8];
    float* out = (float*)d_out;

    char* ws = (char*)d_ws;
    float* vmean           = (float*)(ws);                                        // 16 KiB
    size_t off = 32768;
    unsigned short* Qb     = (unsigned short*)(ws + off);                         // 16 MiB
    unsigned short* Kb     = (unsigned short*)(ws + off + (size_t)16*1024*1024);  // 16 MiB
    unsigned short* Vt     = (unsigned short*)(ws + off + (size_t)32*1024*1024);  // 16 MiB
    unsigned short* Sp     = (unsigned short*)(ws + off + (size_t)48*1024*1024);  // 64 MiB

    hipMemsetAsync(vmean, 0, 4096*sizeof(float), stream);   // capture-legal memset node
    hipLaunchKernelGGL(k_conv,    dim3(3072),      dim3(256), 0, stream,
                       Q, K, V, Qb, Kb, Vt, vmean);
    hipLaunchKernelGGL(k_gemm_qk, dim3(16, 16, 8), dim3(256), 0, stream,
                       Qb, Kb, ps, pb, Sp);
    hipLaunchKernelGGL(k_gemm_pv, dim3(512),       dim3(256), 0, stream,
                       Sp, Vt, vmean, w1, b1, w2, b2, out);
}

// Round 7
// 259.405 us; speedup vs baseline: 1.0263x; 1.0263x over previous
//
#include <hip/hip_runtime.h>
#include <cstdint>

#define DEV __device__ __forceinline__

typedef float f32x4 __attribute__((ext_vector_type(4)));
typedef short s16x8 __attribute__((ext_vector_type(8)));

DEV unsigned short f2bf(float f){
    unsigned u = __builtin_bit_cast(unsigned, f);
    u = u + 0x7fffu + ((u >> 16) & 1u);   // RNE
    return (unsigned short)(u >> 16);
}
DEV float bf2f(unsigned short h){
    unsigned u = ((unsigned)h) << 16;
    return __builtin_bit_cast(float, u);
}

typedef const void __attribute__((address_space(1)))* gcp;
typedef void __attribute__((address_space(3)))* lp;
DEV void gload_lds16(const void* g, void* l){
    // async global->LDS, 16B per lane; LDS dest = wave-uniform base + lane*16
    __builtin_amdgcn_global_load_lds((gcp)g, (lp)l, 16, 0, 0);
}

#define SCALE_QK 0.04419417382415922f   // 1/sqrt(512)

// ---------------------------------------------------------------------------
// Dragon pattern: fully input-independent -> computed at COMPILE TIME.
// patterns[11] has length 4095 = 2*2048-1; np.interp to 2048 picks a[2i].
// ---------------------------------------------------------------------------
struct Pat2 { float v[2048]; };
constexpr Pat2 make_pat2(){
    float a[4095] = {}; float b[4095] = {};
    a[0] = 0.5f; int len = 1;
    for (int it = 1; it < 12; ++it){
        int n = len, nl = 2*n + 1;
        for (int i = 0; i < nl; ++i)
            b[i] = (i < n) ? a[i] : ((i == n) ? 0.5f : 1.0f - a[2*n - i]);
        const float third = 1.0f/3.0f;
        float mn = 3.4e38f, mx = -3.4e38f;
        for (int i = 0; i < nl; ++i){
            float s = b[i]*third;
            if (i > 0)      s += b[i-1]*third;
            if (i < nl - 1) s += b[i+1]*third;
            a[i] = s;
            mn = (s < mn) ? s : mn;
            mx = (s > mx) ? s : mx;
        }
        float d = mx - mn + 1e-8f;
        for (int i = 0; i < nl; ++i) a[i] = (a[i] - mn) / d;
        len = nl;
    }
    Pat2 p{};
    for (int i = 0; i < 2048; ++i) p.v[i] = a[2*i];
    return p;
}
__device__ const Pat2 g_pat2 = make_pat2();

// ---------------------------------------------------------------------------
// Conv (grid 4096, balanced streaming):
//   blocks 0..2047   : Q -> bf16, K -> bf16 (raw; dragon weight applied in
//                      gemm_qk epilogue via the identity Q.(Kw)^T = (Q.K^T)w)
//   blocks 2048..4095: V -> Vt (bf16 [b][d][s]) pure transpose
// (vmean is computed inside gemm_pv from its own staged B-fragments.)
// ---------------------------------------------------------------------------
__global__ __launch_bounds__(256) void k_conv(
    const float* __restrict__ Q, const float* __restrict__ K,
    const float* __restrict__ V,
    unsigned short* __restrict__ Qb, unsigned short* __restrict__ Kb,
    unsigned short* __restrict__ Vt)
{
    __shared__ float sh[4224];
    int tid = threadIdx.x;
    int bx  = blockIdx.x;

    if (bx < 2048){
        const long long total4 = (long long)8*2048*512/4;   // 2097152
        long long stride = 2048LL*256;
        for (long long i = (long long)bx*256 + tid; i < total4; i += stride){
            long long base = i*4;
            const float4 q = *(const float4*)(Q + base);
            const float4 k = *(const float4*)(K + base);
            ushort4 qo, ko;
            qo.x = f2bf(q.x); qo.y = f2bf(q.y); qo.z = f2bf(q.z); qo.w = f2bf(q.w);
            ko.x = f2bf(k.x); ko.y = f2bf(k.y); ko.z = f2bf(k.z); ko.w = f2bf(k.w);
            *(ushort4*)(Qb + base) = qo;
            *(ushort4*)(Kb + base) = ko;
        }
        return;
    }

    // ---- V transpose (pure) ----
    int t = bx - 2048;                    // 0..2047 = 32 stile x 8 dtile x 8 b
    int stile = t & 31, dtile = (t >> 5) & 7, b = t >> 8;
    int s0 = stile*64, d0 = dtile*64;
    float (*tile)[66] = (float(*)[66])sh;  // 64x66 pad -> conflict-free
    int tx = tid & 63, ty = tid >> 6;
    const float* src = V + ((long long)b*2048 + s0)*512 + d0;
    #pragma unroll
    for (int r = 0; r < 16; ++r){
        int row = r*4 + ty;
        tile[row][tx] = src[(long long)row*512 + tx];
    }
    __syncthreads();
    unsigned short* dst = Vt + ((long long)b*512 + d0)*2048 + s0;
    #pragma unroll
    for (int r = 0; r < 16; ++r){
        int drow = r*4 + ty;
        dst[(long long)drow*2048 + tx] = f2bf(tile[tx][drow]);
    }
}

// ---------------------------------------------------------------------------
// GEMM 1: Sp[b,q,k] = bf16( exp( (Qb . Kb^T) * softplus(pat[k]*sc+bi)/sqrt(D) ))
// 128x128 tile, BK=64, 4 waves (2x2), 4x4 MFMA 16x16x32.
// LDS = exactly 32768 B -> 5 blocks/CU (the r6 regression showed 35840 B
// drops to 4 blocks/CU = -20%). XOR-swizzled -> 0 bank conflicts.
// ---------------------------------------------------------------------------
__global__ __launch_bounds__(256) void k_gemm_qk(
    const unsigned short* __restrict__ Qb, const unsigned short* __restrict__ Kb,
    const float* __restrict__ scale, const float* __restrict__ bias,
    unsigned short* __restrict__ Sp)
{
    __shared__ unsigned short At[128*64];
    __shared__ unsigned short Bt[128*64];
    int tid = threadIdx.x;
    int lane = tid & 63, wave = tid >> 6;
    int wm = wave >> 1, wn = wave & 1;
    int ln = lane & 15, q4 = lane >> 4;
    int sx = ln & 7;
    int q0 = blockIdx.y*128, k0 = blockIdx.x*128, b = blockIdx.z;
    const unsigned short* Abase = Qb + ((long long)b*2048 + q0)*512;
    const unsigned short* Bbase = Kb + ((long long)b*2048 + k0)*512;

    f32x4 acc[4][4];
    #pragma unroll
    for (int i = 0; i < 4; ++i)
        #pragma unroll
        for (int j = 0; j < 4; ++j) acc[i][j] = (f32x4)0.0f;

    int cc = lane & 7, rg = lane >> 3;
    for (int kt = 0; kt < 8; ++kt){
        #pragma unroll
        for (int c = 0; c < 4; ++c){
            int chunk = wave*4 + c;                 // 16 x 1KB chunks per tile
            int row = chunk*8 + rg;
            int gc  = cc ^ (row & 7);               // swizzled source chunk
            gload_lds16(Abase + (long long)row*512 + kt*64 + gc*8, &At[chunk*512]);
            gload_lds16(Bbase + (long long)row*512 + kt*64 + gc*8, &Bt[chunk*512]);
        }
        __syncthreads();
        #pragma unroll
        for (int ks = 0; ks < 2; ++ks){
            int cs = ((ks*4 + q4) ^ sx) * 8;        // swizzled fragment chunk
            s16x8 af[4], bfr[4];
            #pragma unroll
            for (int i = 0; i < 4; ++i)
                af[i] = *(const s16x8*)&At[(wm*64 + i*16 + ln)*64 + cs];
            #pragma unroll
            for (int j = 0; j < 4; ++j)
                bfr[j] = *(const s16x8*)&Bt[(wn*64 + j*16 + ln)*64 + cs];
            #pragma unroll
            for (int i = 0; i < 4; ++i)
                #pragma unroll
                for (int j = 0; j < 4; ++j)
                    acc[i][j] = __builtin_amdgcn_mfma_f32_16x16x32_bf16(af[i], bfr[j], acc[i][j], 0, 0, 0);
        }
        __syncthreads();
    }

    // epilogue: dragon weight (compile-time pattern + runtime affine), exp,
    // direct stores (r5-proven; LDS repack regressed occupancy in r6)
    float sc = scale[11], bi = bias[11];
    float wq[4];
    #pragma unroll
    for (int j = 0; j < 4; ++j){
        float x = g_pat2.v[k0 + wn*64 + j*16 + ln]*sc + bi;
        wq[j] = (fmaxf(x, 0.f) + log1pf(__expf(-fabsf(x)))) * SCALE_QK;  // softplus
    }
    unsigned short* outp = Sp + (long long)b*2048*2048;
    #pragma unroll
    for (int i = 0; i < 4; ++i){
        #pragma unroll
        for (int j = 0; j < 4; ++j){
            #pragma unroll
            for (int r = 0; r < 4; ++r){
                int q = q0 + wm*64 + i*16 + q4*4 + r;   // C/D: row=(lane>>4)*4+reg
                int k = k0 + wn*64 + j*16 + ln;         //      col=lane&15
                outp[(long long)q*2048 + k] = f2bf(__expf(acc[i][j][r] * wq[j]));
            }
        }
    }
}

// ---------------------------------------------------------------------------
// GEMM 2: out[b,q,d] = blend * (Sp . V) / l[q] + (1-blend) * Vmean[d]
// l[q]     = sum_k Sp[q,k]  from A-fragments (wn==0 waves).
// Vmean[d] = sum_s Vt[d,s]/2048 from B-fragments (all waves; wm==0 writes) —
//            the kt loop covers each staged row's full k-range exactly once.
// blend MLP on wave 0. XCD-aware decode: the 4 d-tiles of one (q,b) pair
// land on the same XCD -> shared Sp rows hit the same L2.
// ---------------------------------------------------------------------------
__global__ __launch_bounds__(256) void k_gemm_pv(
    const unsigned short* __restrict__ Sp, const unsigned short* __restrict__ Vt,
    const float* __restrict__ w1, const float* __restrict__ b1,
    const float* __restrict__ w2, const float* __restrict__ b2,
    float* __restrict__ out)
{
    __shared__ unsigned short At[128*64];
    __shared__ unsigned short Bt[128*64];
    __shared__ float l_sh[128];
    __shared__ float v_sh[128];
    __shared__ float sh_blend;
    int tid = threadIdx.x;
    int lane = tid & 63, wave = tid >> 6;
    int wm = wave >> 1, wn = wave & 1;
    int ln = lane & 15, q4 = lane >> 4;
    int sx = ln & 7;

    // blend (tiny MLP) on wave 0, before staging loop
    if (wave == 0){
        float h = fmaxf(w1[11*64 + lane] + b1[lane], 0.f);
        float c = h * w2[lane];
        #pragma unroll
        for (int off = 32; off > 0; off >>= 1) c += __shfl_xor(c, off, 64);
        if (lane == 0) sh_blend = 1.f/(1.f + __expf(-(c + b2[0])));
    }

    // XCD-aware decode
    int g    = blockIdx.x;             // 0..511
    int xcd  = g & 7, slot = g >> 3;   // slot 0..63
    int pair = xcd*16 + (slot >> 2);   // 0..127
    int dt   = slot & 3;
    int qt   = pair & 15, b = pair >> 4;
    int q0 = qt*128, d0 = dt*128;

    const unsigned short* Abase = Sp + (long long)b*2048*2048 + (long long)q0*2048;
    const unsigned short* Bbase = Vt + ((long long)b*512 + d0)*2048;

    f32x4 acc[4][4];
    #pragma unroll
    for (int i = 0; i < 4; ++i)
        #pragma unroll
        for (int j = 0; j < 4; ++j) acc[i][j] = (f32x4)0.0f;
    float lsum[4] = {0.f, 0.f, 0.f, 0.f};
    float vsum[4] = {0.f, 0.f, 0.f, 0.f};

    int cc = lane & 7, rg = lane >> 3;
    for (int kt = 0; kt < 32; ++kt){
        #pragma unroll
        for (int c = 0; c < 4; ++c){
            int chunk = wave*4 + c;
            int row = chunk*8 + rg;
            int gc  = cc ^ (row & 7);
            gload_lds16(Abase + (long long)row*2048 + kt*64 + gc*8, &At[chunk*512]);
            gload_lds16(Bbase + (long long)row*2048 + kt*64 + gc*8, &Bt[chunk*512]);
        }
        __syncthreads();
        #pragma unroll
        for (int ks = 0; ks < 2; ++ks){
            int cs = ((ks*4 + q4) ^ sx) * 8;
            s16x8 af[4], bfr[4];
            #pragma unroll
            for (int i = 0; i < 4; ++i)
                af[i] = *(const s16x8*)&At[(wm*64 + i*16 + ln)*64 + cs];
            #pragma unroll
            for (int j = 0; j < 4; ++j)
                bfr[j] = *(const s16x8*)&Bt[(wn*64 + j*16 + ln)*64 + cs];
            if (wn == 0){
                #pragma unroll
                for (int i = 0; i < 4; ++i){
                    float s = 0.f;
                    #pragma unroll
                    for (int jj = 0; jj < 8; ++jj) s += bf2f((unsigned short)af[i][jj]);
                    lsum[i] += s;
                }
            }
            #pragma unroll
            for (int j = 0; j < 4; ++j){
                float s = 0.f;
                #pragma unroll
                for (int jj = 0; jj < 8; ++jj) s += bf2f((unsigned short)bfr[j][jj]);
                vsum[j] += s;
            }
            #pragma unroll
            for (int i = 0; i < 4; ++i)
                #pragma unroll
                for (int j = 0; j < 4; ++j)
                    acc[i][j] = __builtin_amdgcn_mfma_f32_16x16x32_bf16(af[i], bfr[j], acc[i][j], 0, 0, 0);
        }
        __syncthreads();
    }
    if (wn == 0){
        #pragma unroll
        for (int i = 0; i < 4; ++i){
            float v = lsum[i];
            v += __shfl_xor(v, 16, 64);
            v += __shfl_xor(v, 32, 64);
            if (lane < 16) l_sh[wm*64 + i*16 + lane] = v;
        }
    }
    // vmean: lanes sharing ln across q4 cover a B-row's full 64-short slice
    #pragma unroll
    for (int j = 0; j < 4; ++j){
        float v = vsum[j];
        v += __shfl_xor(v, 16, 64);
        v += __shfl_xor(v, 32, 64);
        if (wm == 0 && lane < 16) v_sh[wn*64 + j*16 + lane] = v * (1.0f/2048.0f);
    }
    __syncthreads();

    float blend = sh_blend;
    float ib = 1.0f - blend;
    float* obase = out + ((long long)b*2048 + q0)*512 + d0;
    float vm[4];
    #pragma unroll
    for (int j = 0; j < 4; ++j) vm[j] = v_sh[wn*64 + j*16 + ln];
    #pragma unroll
    for (int i = 0; i < 4; ++i){
        #pragma unroll
        for (int r = 0; r < 4; ++r){
            int ql = wm*64 + i*16 + q4*4 + r;
            float linv = 1.0f / l_sh[ql];
            #pragma unroll
            for (int j = 0; j < 4; ++j){
                int dl = wn*64 + j*16 + ln;
                obase[(long long)ql*512 + dl] = blend*acc[i][j][r]*linv + ib*vm[j];
            }
        }
    }
}

// ---------------------------------------------------------------------------
extern "C" void kernel_launch(void* const* d_in, const int* in_sizes, int n_in,
                              void* d_out, int out_size, void* d_ws, size_t ws_size,
                              hipStream_t stream)
{
    (void)in_sizes; (void)n_in; (void)out_size; (void)ws_size;
    const float* Q  = (const float*)d_in[0];
    const float* K  = (const float*)d_in[1];
    const float* V  = (const float*)d_in[2];
    const float* ps = (const float*)d_in[3];
    const float* pb = (const float*)d_in[4];
    const float* w1 = (const float*)d_in[5];
    const float* b1 = (const float*)d_in[6];
    const float* w2 = (const float*)d_in[7];
    const float* b2 = (const float*)d_in[8];
    float* out = (float*)d_out;

    char* ws = (char*)d_ws;
    unsigned short* Qb     = (unsigned short*)(ws);                               // 16 MiB
    unsigned short* Kb     = (unsigned short*)(ws + (size_t)16*1024*1024);        // 16 MiB
    unsigned short* Vt     = (unsigned short*)(ws + (size_t)32*1024*1024);        // 16 MiB
    unsigned short* Sp     = (unsigned short*)(ws + (size_t)48*1024*1024);        // 64 MiB

    hipLaunchKernelGGL(k_conv,    dim3(4096),      dim3(256), 0, stream,
                       Q, K, V, Qb, Kb, Vt);
    hipLaunchKernelGGL(k_gemm_qk, dim3(16, 16, 8), dim3(256), 0, stream,
                       Qb, Kb, ps, pb, Sp);
    hipLaunchKernelGGL(k_gemm_pv, dim3(512),       dim3(256), 0, stream,
                       Sp, Vt, w1, b1, w2, b2, out);
}